// Round 2
// baseline (3449.809 us; speedup 1.0000x reference)
//
#include <hip/hip_runtime.h>
#include <math.h>

// SLAYER MLP forward: spike(psp(W2 @ spike(psp(W1 @ x))))
// B=256, IN=78, HID=16, OUT=20, T=1000, K=100 (SRM alpha, tau=10)
// fp64 accumulation everywhere (passed absmax 0.0 in round 0); fp32 rounding
// applied where the reference materializes tensors (einsum out, final u).

#define B_     256
#define IN_    78
#define HID_   16
#define OUT_   20
#define T_     1000
#define TT_    125
#define NTILE_ 8
#define J_     224            // TT + K - 1
#define ZROW_  256            // zs row stride (floats), 64 16B-blocks for XOR swizzle
#define ICH_   13             // L1 input-channel chunk (78 = 6*13)

// ---- FIR building blocks -------------------------------------------------
// window [WA|WB|WC] = z[base .. base+11] (doubles); does taps s0=104-4g..+3,
// then loads the next quad (becomes the tail after rotation) into WA.
#define ZWIDX(k, WA, WB, WC) ((k) < 4 ? WA[(k)] : ((k) < 8 ? WB[(k)-4] : WC[(k)-8]))
#define GRP(g, WA, WB, WC) { \
  const float4 e4 = *(const float4*)&epsf[104 - 4*(g)]; \
  const double e0 = (double)e4.x, e1 = (double)e4.y, e2 = (double)e4.z, e3 = (double)e4.w; \
  _Pragma("unroll") \
  for (int d = 0; d < 8; ++d) { \
    u[d] += e0 * ZWIDX(d+3, WA, WB, WC); \
    u[d] += e1 * ZWIDX(d+2, WA, WB, WC); \
    u[d] += e2 * ZWIDX(d+1, WA, WB, WC); \
    u[d] += e3 * ZWIDX(d+0, WA, WB, WC); \
  } \
  { const float4 fn = z4[rb + ((2*q + (g) + 3) ^ sw)]; \
    WA[0] = (double)fn.x; WA[1] = (double)fn.y; WA[2] = (double)fn.z; WA[3] = (double)fn.w; } \
}
#define TRI(g0, WA, WB, WC) GRP(g0, WA, WB, WC) GRP((g0)+1, WB, WC, WA) GRP((g0)+2, WC, WA, WB)

__device__ __forceinline__ void init_eps(float* epsf, int tid) {
  if (tid < 108) {
    float v = 0.0f;
    if (tid < 100) { float a = (float)tid * 0.1f; v = a * expf(1.0f - a); }
    epsf[tid] = v;
  }
}

// ---- Layer 1: x[256,78,1000] -> s1[256,16,1000] --------------------------
__global__ __launch_bounds__(256, 4) void slayer_l1(
    const float* __restrict__ x, const float* __restrict__ W1,
    float* __restrict__ s1)
{
  __shared__ float xs[ICH_ * 280];   // [i][c*20 + d], 14 chunks of 16 + 4 pad
  __shared__ float zs[HID_ * ZROW_]; // swizzled; logical dword = 8 + j (8 left pad)
  __shared__ float w[HID_ * IN_];
  __shared__ float epsf[108];        // eps padded with zeros to 108 taps

  const int tid  = threadIdx.x;
  const int b    = blockIdx.x >> 3;
  const int tile = blockIdx.x & 7;
  const int t0   = tile * TT_;

  for (int idx = tid; idx < HID_ * IN_; idx += 256) w[idx] = W1[idx];
  init_eps(epsf, tid);
  { // zero zs pad columns: logical dwords 0..7 and 232..239 (through swizzle)
    const int h = tid >> 4, col = tid & 15;
    const int p = (col < 8) ? col : (col + 224);
    zs[h * ZROW_ + ((((p >> 2) ^ (h & 7)) << 2) | (p & 3))] = 0.0f;
  }

  // ---- matmul: z[h][j] = sum_i W1[h][i] * x[b][i][t0-99+j] ----
  double acc[16];
#pragma unroll
  for (int k = 0; k < 16; ++k) acc[k] = 0.0;
  const int  hM  = tid / 14;            // 0..15 when tid<224
  const int  cM  = tid - hM * 14;       // chunk 0..13
  const bool mOK = tid < 224;

  const int  jj   = tid;                // staging column (0..223 active)
  const int  tg   = t0 - 99 + jj;       // global t for this column
  const int  xoff = ((jj >> 4) * 20) + (jj & 15);
  const bool sOK  = jj < J_;

  for (int ci = 0; ci < 6; ++ci) {
    __syncthreads();
    if (sOK) {
      if (tg >= 0) {
        const float* xp = x + ((size_t)b * IN_ + ci * ICH_) * T_ + tg;
#pragma unroll
        for (int i = 0; i < ICH_; ++i) xs[i * 280 + xoff] = xp[i * T_];
      } else {
#pragma unroll
        for (int i = 0; i < ICH_; ++i) xs[i * 280 + xoff] = 0.0f;
      }
    }
    __syncthreads();
    if (mOK) {
      const int wbase = hM * IN_ + ci * ICH_;
#pragma unroll
      for (int i = 0; i < ICH_; ++i) {
        const double wv = (double)w[wbase + i];
        const float4* p4 = (const float4*)&xs[i * 280 + cM * 20];
        const float4 v0 = p4[0], v1 = p4[1], v2 = p4[2], v3 = p4[3];
        acc[0]  += wv * (double)v0.x;  acc[1]  += wv * (double)v0.y;
        acc[2]  += wv * (double)v0.z;  acc[3]  += wv * (double)v0.w;
        acc[4]  += wv * (double)v1.x;  acc[5]  += wv * (double)v1.y;
        acc[6]  += wv * (double)v1.z;  acc[7]  += wv * (double)v1.w;
        acc[8]  += wv * (double)v2.x;  acc[9]  += wv * (double)v2.y;
        acc[10] += wv * (double)v2.z;  acc[11] += wv * (double)v2.w;
        acc[12] += wv * (double)v3.x;  acc[13] += wv * (double)v3.y;
        acc[14] += wv * (double)v3.z;  acc[15] += wv * (double)v3.w;
      }
    }
  }
  if (mOK) { // write z (fp32-rounded) at logical dwords 8+16c .. +15, swizzled
    float4* z4w = (float4*)zs;
    const int rbw = (hM * ZROW_) >> 2;
    const int swm = hM & 7;
#pragma unroll
    for (int wq = 0; wq < 4; ++wq) {
      float4 v;
      v.x = (float)acc[wq * 4 + 0]; v.y = (float)acc[wq * 4 + 1];
      v.z = (float)acc[wq * 4 + 2]; v.w = (float)acc[wq * 4 + 3];
      z4w[rbw + ((2 + 4 * cM + wq) ^ swm)] = v;
    }
  }
  __syncthreads();

  // ---- FIR + threshold: u[tt] = sum_s eps[s] * z[tt+99-s] ----
  {
    const int h = tid >> 4, q = tid & 15;
    const int ttb = q * 8;
    const float4* z4 = (const float4*)zs;
    const int rb = (h * ZROW_) >> 2;
    const int sw = h & 7;
    double u[8];
#pragma unroll
    for (int d = 0; d < 8; ++d) u[d] = 0.0;
    double A[4], B[4], C[4];
    { float4 f = z4[rb + ((2 * q + 0) ^ sw)];
      A[0]=(double)f.x; A[1]=(double)f.y; A[2]=(double)f.z; A[3]=(double)f.w; }
    { float4 f = z4[rb + ((2 * q + 1) ^ sw)];
      B[0]=(double)f.x; B[1]=(double)f.y; B[2]=(double)f.z; B[3]=(double)f.w; }
    { float4 f = z4[rb + ((2 * q + 2) ^ sw)];
      C[0]=(double)f.x; C[1]=(double)f.y; C[2]=(double)f.z; C[3]=(double)f.w; }
    TRI(0,A,B,C) TRI(3,A,B,C) TRI(6,A,B,C) TRI(9,A,B,C) TRI(12,A,B,C)
    TRI(15,A,B,C) TRI(18,A,B,C) TRI(21,A,B,C) TRI(24,A,B,C)
    const size_t sbase = ((size_t)b * HID_ + h) * T_ + t0;
#pragma unroll
    for (int d = 0; d < 8; ++d) {
      const int tt = ttb + d;
      if (tt < TT_) {
        const float uf = (float)u[d];
        s1[sbase + tt] = (uf >= 1.0f) ? 1.0f : 0.0f;
      }
    }
  }
}

// ---- Layer 2: s1[256,16,1000] -> out[256,20,1000] ------------------------
__global__ __launch_bounds__(256, 4) void slayer_l2(
    const float* __restrict__ s1, const float* __restrict__ W2,
    float* __restrict__ out)
{
  __shared__ float ss[HID_ * 140];   // half j-range: 7 chunks of (16+4)
  __shared__ float zs[OUT_ * ZROW_];
  __shared__ float w[OUT_ * HID_];
  __shared__ float epsf[108];

  const int tid  = threadIdx.x;
  const int b    = blockIdx.x >> 3;
  const int tile = blockIdx.x & 7;
  const int t0   = tile * TT_;

  for (int idx = tid; idx < OUT_ * HID_; idx += 256) w[idx] = W2[idx];
  init_eps(epsf, tid);
  for (int p0 = tid; p0 < OUT_ * 16; p0 += 256) { // zero zs pads
    const int h = p0 >> 4, col = p0 & 15;
    const int p = (col < 8) ? col : (col + 224);
    zs[h * ZROW_ + ((((p >> 2) ^ (h & 7)) << 2) | (p & 3))] = 0.0f;
  }

  const int  hM  = tid / 7;             // 0..19 when tid<140
  const int  cL  = tid - hM * 7;        // local chunk 0..6
  const bool mOK = tid < 140;

  const int  r2  = tid / 112;           // staging: 2 rows per pass
  const int  jj  = tid - r2 * 112;      // 0..111
  const bool sOK = tid < 224;
  const int  soff = ((jj >> 4) * 20) + (jj & 15);

  for (int hj = 0; hj < 2; ++hj) {
    __syncthreads();
    if (sOK) {
      const int tg = t0 - 99 + hj * 112 + jj;
      if (tg >= 0) {
        const float* sp = s1 + ((size_t)b * HID_ + r2) * T_ + tg;
#pragma unroll
        for (int i = 0; i < 8; ++i) ss[(r2 + 2 * i) * 140 + soff] = sp[2 * i * T_];
      } else {
#pragma unroll
        for (int i = 0; i < 8; ++i) ss[(r2 + 2 * i) * 140 + soff] = 0.0f;
      }
    }
    __syncthreads();
    if (mOK) {
      double acc[16];
#pragma unroll
      for (int k = 0; k < 16; ++k) acc[k] = 0.0;
      const int wbase = hM * HID_;
#pragma unroll
      for (int i = 0; i < HID_; ++i) {
        const double wv = (double)w[wbase + i];
        const float4* p4 = (const float4*)&ss[i * 140 + cL * 20];
        const float4 v0 = p4[0], v1 = p4[1], v2 = p4[2], v3 = p4[3];
        acc[0]  += wv * (double)v0.x;  acc[1]  += wv * (double)v0.y;
        acc[2]  += wv * (double)v0.z;  acc[3]  += wv * (double)v0.w;
        acc[4]  += wv * (double)v1.x;  acc[5]  += wv * (double)v1.y;
        acc[6]  += wv * (double)v1.z;  acc[7]  += wv * (double)v1.w;
        acc[8]  += wv * (double)v2.x;  acc[9]  += wv * (double)v2.y;
        acc[10] += wv * (double)v2.z;  acc[11] += wv * (double)v2.w;
        acc[12] += wv * (double)v3.x;  acc[13] += wv * (double)v3.y;
        acc[14] += wv * (double)v3.z;  acc[15] += wv * (double)v3.w;
      }
      float4* z4w = (float4*)zs;
      const int rbw = (hM * ZROW_) >> 2;
      const int swm = hM & 7;
      const int cG  = hj * 7 + cL;
#pragma unroll
      for (int wq = 0; wq < 4; ++wq) {
        float4 v;
        v.x = (float)acc[wq * 4 + 0]; v.y = (float)acc[wq * 4 + 1];
        v.z = (float)acc[wq * 4 + 2]; v.w = (float)acc[wq * 4 + 3];
        z4w[rbw + ((2 + 4 * cG + wq) ^ swm)] = v;
      }
    }
  }
  __syncthreads();

  // FIR + threshold: 20*16 = 320 tasks
  for (int task = tid; task < OUT_ * 16; task += 256) {
    const int h = task >> 4, q = task & 15;
    const int ttb = q * 8;
    const float4* z4 = (const float4*)zs;
    const int rb = (h * ZROW_) >> 2;
    const int sw = h & 7;
    double u[8];
#pragma unroll
    for (int d = 0; d < 8; ++d) u[d] = 0.0;
    double A[4], B[4], C[4];
    { float4 f = z4[rb + ((2 * q + 0) ^ sw)];
      A[0]=(double)f.x; A[1]=(double)f.y; A[2]=(double)f.z; A[3]=(double)f.w; }
    { float4 f = z4[rb + ((2 * q + 1) ^ sw)];
      B[0]=(double)f.x; B[1]=(double)f.y; B[2]=(double)f.z; B[3]=(double)f.w; }
    { float4 f = z4[rb + ((2 * q + 2) ^ sw)];
      C[0]=(double)f.x; C[1]=(double)f.y; C[2]=(double)f.z; C[3]=(double)f.w; }
    TRI(0,A,B,C) TRI(3,A,B,C) TRI(6,A,B,C) TRI(9,A,B,C) TRI(12,A,B,C)
    TRI(15,A,B,C) TRI(18,A,B,C) TRI(21,A,B,C) TRI(24,A,B,C)
    const size_t obase = ((size_t)b * OUT_ + h) * T_ + t0;
#pragma unroll
    for (int d = 0; d < 8; ++d) {
      const int tt = ttb + d;
      if (tt < TT_) {
        const float uf = (float)u[d];
        out[obase + tt] = (uf >= 1.0f) ? 1.0f : 0.0f;
      }
    }
  }
}

extern "C" void kernel_launch(void* const* d_in, const int* in_sizes, int n_in,
                              void* d_out, int out_size, void* d_ws, size_t ws_size,
                              hipStream_t stream) {
  const float* x  = (const float*)d_in[0];
  const float* W1 = (const float*)d_in[1];
  const float* W2 = (const float*)d_in[2];
  float* outp = (float*)d_out;
  float* s1   = (float*)d_ws;      // [256,16,1000] f32 = 16.384 MB

  dim3 grid(B_ * NTILE_), block(256);
  slayer_l1<<<grid, block, 0, stream>>>(x, W1, s1);
  slayer_l2<<<grid, block, 0, stream>>>(s1, W2, outp);
}

// Round 3
// 1240.804 us; speedup vs baseline: 2.7803x; 2.7803x over previous
//
#include <hip/hip_runtime.h>
#include <math.h>

// SLAYER MLP forward: spike(psp(W2 @ spike(psp(W1 @ x))))
// B=256, IN=78, HID=16, OUT=20, T=1000, K=100 (SRM alpha, tau=10)
//
// fp64 accumulation everywhere (matched reference exactly in rounds 0-2),
// fp32 rounding applied exactly where the reference materializes tensors
// (einsum outputs z1/z2, final u before threshold compare).
//
// Round-3 rule: NO local arrays in hot code (round-2 spilled them to scratch:
// 4.9 GB HBM traffic, VALUBusy 1.5%). Everything is named scalar doubles.

#define B_     256
#define IN_    78
#define HID_   16
#define OUT_   20
#define T_     1000
#define TT_    125
#define J_     224              // TT + K - 1

// ---------------- FIR building blocks (named scalars only) ----------------
// Window W[0..10] = quads (A,B,C): A=lowest 4, B=next 4, C0..C2.
// Group with eps[s0..s0+3]:  u[d] += eps[s0+e] * W[d-e+3]
#define GRP(EP, A0,A1,A2,A3, B0,B1,B2,B3, C0,C1,C2) { \
  const double2 e01_ = *(const double2*)(EP); \
  const double2 e23_ = *(const double2*)((EP)+2); \
  u0 += e01_.x*(A3); u1 += e01_.x*(B0); u2 += e01_.x*(B1); u3 += e01_.x*(B2); \
  u4 += e01_.x*(B3); u5 += e01_.x*(C0); u6 += e01_.x*(C1); u7 += e01_.x*(C2); \
  u0 += e01_.y*(A2); u1 += e01_.y*(A3); u2 += e01_.y*(B0); u3 += e01_.y*(B1); \
  u4 += e01_.y*(B2); u5 += e01_.y*(B3); u6 += e01_.y*(C0); u7 += e01_.y*(C1); \
  u0 += e23_.x*(A1); u1 += e23_.x*(A2); u2 += e23_.x*(A3); u3 += e23_.x*(B0); \
  u4 += e23_.x*(B1); u5 += e23_.x*(B2); u6 += e23_.x*(B3); u7 += e23_.x*(C0); \
  u0 += e23_.y*(A0); u1 += e23_.y*(A1); u2 += e23_.y*(A2); u3 += e23_.y*(A3); \
  u4 += e23_.y*(B0); u5 += e23_.y*(B1); u6 += e23_.y*(B2); u7 += e23_.y*(B3); }

#define LOADD(X0,X1,X2,X3, P) { \
  const double2 la_ = *(const double2*)(P); \
  const double2 lb_ = *(const double2*)((P)+2); \
  X0 = la_.x; X1 = la_.y; X2 = lb_.x; X3 = lb_.y; }

#define LOADF(X0,X1,X2,X3, P) { \
  const float4 lf_ = *(const float4*)(P); \
  X0 = (double)lf_.x; X1 = (double)lf_.y; X2 = (double)lf_.z; X3 = (double)lf_.w; }

// fp64-plane step: load quad c=24-G (plane by parity, slot q + (24-G)/2), then GRP.
// Requires in scope: q, ze_row, zo_row (double*), eps_d, u0..u7.
#define STEPD(G, N0,N1,N2,N3, P0,P1,P2,P3, Q0,Q1,Q2) \
  LOADD(N0,N1,N2,N3, ((((24-(G))&1) ? zo_row : ze_row) + 4*(q + ((24-(G))>>1)))); \
  GRP(eps_d + 4*(G), N0,N1,N2,N3, P0,P1,P2,P3, Q0,Q1,Q2)

// fp32-plane step (for layer-2 z): requires zef_row, zof_row (float*).
#define STEPF(G, N0,N1,N2,N3, P0,P1,P2,P3, Q0,Q1,Q2) \
  LOADF(N0,N1,N2,N3, ((((24-(G))&1) ? zof_row : zef_row) + 4*(q + ((24-(G))>>1)))); \
  GRP(eps_d + 4*(G), N0,N1,N2,N3, P0,P1,P2,P3, Q0,Q1,Q2)

#define FIR24_D \
  STEPD( 1, C0,C1,C2,C3, A0,A1,A2,A3, B0,B1,B2) \
  STEPD( 2, B0,B1,B2,B3, C0,C1,C2,C3, A0,A1,A2) \
  STEPD( 3, A0,A1,A2,A3, B0,B1,B2,B3, C0,C1,C2) \
  STEPD( 4, C0,C1,C2,C3, A0,A1,A2,A3, B0,B1,B2) \
  STEPD( 5, B0,B1,B2,B3, C0,C1,C2,C3, A0,A1,A2) \
  STEPD( 6, A0,A1,A2,A3, B0,B1,B2,B3, C0,C1,C2) \
  STEPD( 7, C0,C1,C2,C3, A0,A1,A2,A3, B0,B1,B2) \
  STEPD( 8, B0,B1,B2,B3, C0,C1,C2,C3, A0,A1,A2) \
  STEPD( 9, A0,A1,A2,A3, B0,B1,B2,B3, C0,C1,C2) \
  STEPD(10, C0,C1,C2,C3, A0,A1,A2,A3, B0,B1,B2) \
  STEPD(11, B0,B1,B2,B3, C0,C1,C2,C3, A0,A1,A2) \
  STEPD(12, A0,A1,A2,A3, B0,B1,B2,B3, C0,C1,C2) \
  STEPD(13, C0,C1,C2,C3, A0,A1,A2,A3, B0,B1,B2) \
  STEPD(14, B0,B1,B2,B3, C0,C1,C2,C3, A0,A1,A2) \
  STEPD(15, A0,A1,A2,A3, B0,B1,B2,B3, C0,C1,C2) \
  STEPD(16, C0,C1,C2,C3, A0,A1,A2,A3, B0,B1,B2) \
  STEPD(17, B0,B1,B2,B3, C0,C1,C2,C3, A0,A1,A2) \
  STEPD(18, A0,A1,A2,A3, B0,B1,B2,B3, C0,C1,C2) \
  STEPD(19, C0,C1,C2,C3, A0,A1,A2,A3, B0,B1,B2) \
  STEPD(20, B0,B1,B2,B3, C0,C1,C2,C3, A0,A1,A2) \
  STEPD(21, A0,A1,A2,A3, B0,B1,B2,B3, C0,C1,C2) \
  STEPD(22, C0,C1,C2,C3, A0,A1,A2,A3, B0,B1,B2) \
  STEPD(23, B0,B1,B2,B3, C0,C1,C2,C3, A0,A1,A2) \
  STEPD(24, A0,A1,A2,A3, B0,B1,B2,B3, C0,C1,C2)

#define FIR24_F \
  STEPF( 1, C0,C1,C2,C3, A0,A1,A2,A3, B0,B1,B2) \
  STEPF( 2, B0,B1,B2,B3, C0,C1,C2,C3, A0,A1,A2) \
  STEPF( 3, A0,A1,A2,A3, B0,B1,B2,B3, C0,C1,C2) \
  STEPF( 4, C0,C1,C2,C3, A0,A1,A2,A3, B0,B1,B2) \
  STEPF( 5, B0,B1,B2,B3, C0,C1,C2,C3, A0,A1,A2) \
  STEPF( 6, A0,A1,A2,A3, B0,B1,B2,B3, C0,C1,C2) \
  STEPF( 7, C0,C1,C2,C3, A0,A1,A2,A3, B0,B1,B2) \
  STEPF( 8, B0,B1,B2,B3, C0,C1,C2,C3, A0,A1,A2) \
  STEPF( 9, A0,A1,A2,A3, B0,B1,B2,B3, C0,C1,C2) \
  STEPF(10, C0,C1,C2,C3, A0,A1,A2,A3, B0,B1,B2) \
  STEPF(11, B0,B1,B2,B3, C0,C1,C2,C3, A0,A1,A2) \
  STEPF(12, A0,A1,A2,A3, B0,B1,B2,B3, C0,C1,C2) \
  STEPF(13, C0,C1,C2,C3, A0,A1,A2,A3, B0,B1,B2) \
  STEPF(14, B0,B1,B2,B3, C0,C1,C2,C3, A0,A1,A2) \
  STEPF(15, A0,A1,A2,A3, B0,B1,B2,B3, C0,C1,C2) \
  STEPF(16, C0,C1,C2,C3, A0,A1,A2,A3, B0,B1,B2) \
  STEPF(17, B0,B1,B2,B3, C0,C1,C2,C3, A0,A1,A2) \
  STEPF(18, A0,A1,A2,A3, B0,B1,B2,B3, C0,C1,C2) \
  STEPF(19, C0,C1,C2,C3, A0,A1,A2,A3, B0,B1,B2) \
  STEPF(20, B0,B1,B2,B3, C0,C1,C2,C3, A0,A1,A2) \
  STEPF(21, A0,A1,A2,A3, B0,B1,B2,B3, C0,C1,C2) \
  STEPF(22, C0,C1,C2,C3, A0,A1,A2,A3, B0,B1,B2) \
  STEPF(23, B0,B1,B2,B3, C0,C1,C2,C3, A0,A1,A2) \
  STEPF(24, A0,A1,A2,A3, B0,B1,B2,B3, C0,C1,C2)

__device__ __forceinline__ void init_eps_d(double* eps_d, int tid) {
  if (tid < 100) {
    float a = (float)tid / 10.0f;           // identical fp32 ops to reference
    float e = a * expf(1.0f - a);
    eps_d[tid] = (double)e;                 // exact widening
  }
}

// -------- Kernel A: z1[b,h,t] = sum_i W1[h,i] * x[b,i,t]  (no halo) -------
// grid = 256 b * 4 t-chunks of 256;  block 256 = 8 h-pairs * 32 t-octets
__global__ __launch_bounds__(256) void mm1(
    const float* __restrict__ x, const float* __restrict__ W1,
    float* __restrict__ z1)
{
  __shared__ double xe[13 * 128];    // even-quad plane, 13 i-rows x 128
  __shared__ double xo[13 * 128];    // odd-quad plane
  __shared__ double wd[16 * 80];     // W1 fp64, row stride 80

  const int tid = threadIdx.x;
  const int b   = blockIdx.x >> 2;
  const int tc  = blockIdx.x & 3;
  const int tcb = tc * 256;

  for (int idx = tid; idx < HID_ * IN_; idx += 256)
    wd[(idx / IN_) * 80 + (idx % IN_)] = (double)W1[idx];

  // staging map: thread owns column c = tid (fixed plane/slot)
  const int c    = tid;
  const int slot = ((c >> 3) << 2) | (c & 3);
  double* dst = (((c >> 2) & 1) ? xo : xe) + slot;
  const int t_c  = tcb + c;
  const bool cok = (t_c < T_);

  const int p = tid >> 5;            // h-pair 0..7
  const int q = tid & 31;            // t-octet 0..31

  double m00=0,m01=0,m02=0,m03=0,m04=0,m05=0,m06=0,m07=0;
  double m10=0,m11=0,m12=0,m13=0,m14=0,m15=0,m16=0,m17=0;

  for (int ci = 0; ci < 6; ++ci) {
    __syncthreads();
    {
      const float* xp = x + ((size_t)b * IN_ + ci * 13) * T_ + t_c;
#pragma unroll
      for (int r = 0; r < 13; ++r)
        dst[r * 128] = cok ? (double)xp[r * T_] : 0.0;
    }
    __syncthreads();
#pragma unroll
    for (int i = 0; i < 13; ++i) {
      double d0,d1,d2,d3,d4,d5,d6,d7;
      LOADD(d0,d1,d2,d3, &xe[i * 128 + 4 * q]);
      LOADD(d4,d5,d6,d7, &xo[i * 128 + 4 * q]);
      const double w0 = wd[(2*p)     * 80 + ci * 13 + i];
      const double w1 = wd[(2*p + 1) * 80 + ci * 13 + i];
      m00 += w0*d0; m01 += w0*d1; m02 += w0*d2; m03 += w0*d3;
      m04 += w0*d4; m05 += w0*d5; m06 += w0*d6; m07 += w0*d7;
      m10 += w1*d0; m11 += w1*d1; m12 += w1*d2; m13 += w1*d3;
      m14 += w1*d4; m15 += w1*d5; m16 += w1*d6; m17 += w1*d7;
    }
  }

  const int t8 = tcb + 8 * q;
  if (t8 + 7 < T_) {                 // T_ % 8 == 0: octets never straddle
    float* o0 = &z1[((size_t)b * HID_ + 2*p) * T_ + t8];
    float* o1 = &z1[((size_t)b * HID_ + 2*p + 1) * T_ + t8];
    *(float4*)(o0)     = make_float4((float)m00,(float)m01,(float)m02,(float)m03);
    *(float4*)(o0 + 4) = make_float4((float)m04,(float)m05,(float)m06,(float)m07);
    *(float4*)(o1)     = make_float4((float)m10,(float)m11,(float)m12,(float)m13);
    *(float4*)(o1 + 4) = make_float4((float)m14,(float)m15,(float)m16,(float)m17);
  }
}

// -------- Kernel B: s1 = spike(FIR(z1)) ------------------------------------
// tile_fixed < 0: grid = 256b*8tiles; else grid = 256b, single tile (may alias
// zin==sout: in-place is safe when tiles are launched in DESCENDING order).
__global__ __launch_bounds__(256) void fir1(
    const float* __restrict__ zin, float* __restrict__ sout, int tile_fixed)
{
  __shared__ double ze[HID_ * 116];  // even-quad plane, row stride 116 (stagger)
  __shared__ double zo[HID_ * 116];
  __shared__ __align__(16) double eps_d[100];

  const int tid  = threadIdx.x;
  const int b    = (tile_fixed >= 0) ? (int)blockIdx.x : (int)(blockIdx.x >> 3);
  const int tile = (tile_fixed >= 0) ? tile_fixed      : (int)(blockIdx.x & 7);
  const int t0   = tile * TT_;

  init_eps_d(eps_d, tid);
  for (int idx = tid; idx < HID_ * J_; idx += 256) {
    const int r = idx / J_, cc = idx % J_;
    const int t = t0 - 99 + cc;
    const double v = (t >= 0) ? (double)zin[((size_t)b * HID_ + r) * T_ + t] : 0.0;
    double* pl = (((cc >> 2) & 1) ? zo : ze);
    pl[r * 116 + (((cc >> 3) << 2) | (cc & 3))] = v;
  }
  __syncthreads();

  const int h = tid >> 4, q = tid & 15;
  double* ze_row = &ze[h * 116];
  double* zo_row = &zo[h * 116];
  double u0=0,u1=0,u2=0,u3=0,u4=0,u5=0,u6=0,u7=0;
  double A0,A1,A2,A3,B0,B1,B2,B3,C0,C1,C2,C3;
  LOADD(A0,A1,A2,A3, ze_row + 4*(q + 12));     // quad c=24
  LOADD(B0,B1,B2,B3, zo_row + 4*(q + 12));     // quad c=25
  LOADD(C0,C1,C2,C3, ze_row + 4*(q + 13));     // quad c=26
  GRP(eps_d, A0,A1,A2,A3, B0,B1,B2,B3, C0,C1,C2)
  FIR24_D

  const size_t base = ((size_t)b * HID_ + h) * T_ + t0 + 8 * q;
  const int tb = 8 * q;
  {
    const float f0=(float)u0, f1=(float)u1, f2=(float)u2, f3=(float)u3;
    const float f4=(float)u4, f5=(float)u5, f6=(float)u6, f7=(float)u7;
    sout[base + 0] = (f0 >= 1.0f) ? 1.0f : 0.0f;   // tb+3 <= 123 always valid
    sout[base + 1] = (f1 >= 1.0f) ? 1.0f : 0.0f;
    sout[base + 2] = (f2 >= 1.0f) ? 1.0f : 0.0f;
    sout[base + 3] = (f3 >= 1.0f) ? 1.0f : 0.0f;
    if (tb + 4 < TT_) sout[base + 4] = (f4 >= 1.0f) ? 1.0f : 0.0f;
    if (tb + 5 < TT_) sout[base + 5] = (f5 >= 1.0f) ? 1.0f : 0.0f;
    if (tb + 6 < TT_) sout[base + 6] = (f6 >= 1.0f) ? 1.0f : 0.0f;
    if (tb + 7 < TT_) sout[base + 7] = (f7 >= 1.0f) ? 1.0f : 0.0f;
  }
}

// -------- Kernel C+D fused: out = spike(FIR(round32(W2 @ s1))) -------------
// grid = 256b*8tiles, block 320 (matmul: 10 o-pairs x 28 octets; FIR: 20h x 16q)
__global__ __launch_bounds__(320) void l2fused(
    const float* __restrict__ s1, const float* __restrict__ W2,
    float* __restrict__ out)
{
  __shared__ double ss_e[HID_ * 112];
  __shared__ double ss_o[HID_ * 112];
  __shared__ double wd2[OUT_ * HID_];
  __shared__ float  zef[OUT_ * 116];   // z2 fp32 (reference materialization)
  __shared__ float  zof[OUT_ * 116];
  __shared__ __align__(16) double eps_d[100];

  const int tid  = threadIdx.x;
  const int b    = blockIdx.x >> 3;
  const int tile = blockIdx.x & 7;
  const int t0   = tile * TT_;

  init_eps_d(eps_d, tid);
  if (tid < OUT_ * HID_) wd2[tid] = (double)W2[tid];
  for (int idx = tid; idx < HID_ * J_; idx += 320) {
    const int r = idx / J_, cc = idx % J_;
    const int t = t0 - 99 + cc;
    const double v = (t >= 0) ? (double)s1[((size_t)b * HID_ + r) * T_ + t] : 0.0;
    double* pl = (((cc >> 2) & 1) ? ss_o : ss_e);
    pl[r * 112 + (((cc >> 3) << 2) | (cc & 3))] = v;
  }
  __syncthreads();

  { // matmul2 over j = 0..223
    const int p  = tid >> 5;        // o-pair 0..9
    const int q5 = tid & 31;        // octet, active < 28
    if (q5 < 28) {
      double n00=0,n01=0,n02=0,n03=0,n04=0,n05=0,n06=0,n07=0;
      double n10=0,n11=0,n12=0,n13=0,n14=0,n15=0,n16=0,n17=0;
#pragma unroll
      for (int i = 0; i < HID_; ++i) {
        double d0,d1,d2,d3,d4,d5,d6,d7;
        LOADD(d0,d1,d2,d3, &ss_e[i * 112 + 4 * q5]);
        LOADD(d4,d5,d6,d7, &ss_o[i * 112 + 4 * q5]);
        const double w0 = wd2[(2*p)     * HID_ + i];
        const double w1 = wd2[(2*p + 1) * HID_ + i];
        n00 += w0*d0; n01 += w0*d1; n02 += w0*d2; n03 += w0*d3;
        n04 += w0*d4; n05 += w0*d5; n06 += w0*d6; n07 += w0*d7;
        n10 += w1*d0; n11 += w1*d1; n12 += w1*d2; n13 += w1*d3;
        n14 += w1*d4; n15 += w1*d5; n16 += w1*d6; n17 += w1*d7;
      }
      *(float4*)&zef[(2*p)   * 116 + 4*q5] = make_float4((float)n00,(float)n01,(float)n02,(float)n03);
      *(float4*)&zof[(2*p)   * 116 + 4*q5] = make_float4((float)n04,(float)n05,(float)n06,(float)n07);
      *(float4*)&zef[(2*p+1) * 116 + 4*q5] = make_float4((float)n10,(float)n11,(float)n12,(float)n13);
      *(float4*)&zof[(2*p+1) * 116 + 4*q5] = make_float4((float)n14,(float)n15,(float)n16,(float)n17);
    }
  }
  __syncthreads();

  { // FIR2 + threshold: 20 h x 16 q = 320 threads exactly
    const int h = tid >> 4, q = tid & 15;
    float* zef_row = &zef[h * 116];
    float* zof_row = &zof[h * 116];
    double u0=0,u1=0,u2=0,u3=0,u4=0,u5=0,u6=0,u7=0;
    double A0,A1,A2,A3,B0,B1,B2,B3,C0,C1,C2,C3;
    LOADF(A0,A1,A2,A3, zef_row + 4*(q + 12));
    LOADF(B0,B1,B2,B3, zof_row + 4*(q + 12));
    LOADF(C0,C1,C2,C3, zef_row + 4*(q + 13));
    GRP(eps_d, A0,A1,A2,A3, B0,B1,B2,B3, C0,C1,C2)
    FIR24_F

    const size_t base = ((size_t)b * OUT_ + h) * T_ + t0 + 8 * q;
    const int tb = 8 * q;
    const float f0=(float)u0, f1=(float)u1, f2=(float)u2, f3=(float)u3;
    const float f4=(float)u4, f5=(float)u5, f6=(float)u6, f7=(float)u7;
    out[base + 0] = (f0 >= 1.0f) ? 1.0f : 0.0f;
    out[base + 1] = (f1 >= 1.0f) ? 1.0f : 0.0f;
    out[base + 2] = (f2 >= 1.0f) ? 1.0f : 0.0f;
    out[base + 3] = (f3 >= 1.0f) ? 1.0f : 0.0f;
    if (tb + 4 < TT_) out[base + 4] = (f4 >= 1.0f) ? 1.0f : 0.0f;
    if (tb + 5 < TT_) out[base + 5] = (f5 >= 1.0f) ? 1.0f : 0.0f;
    if (tb + 6 < TT_) out[base + 6] = (f6 >= 1.0f) ? 1.0f : 0.0f;
    if (tb + 7 < TT_) out[base + 7] = (f7 >= 1.0f) ? 1.0f : 0.0f;
  }
}

extern "C" void kernel_launch(void* const* d_in, const int* in_sizes, int n_in,
                              void* d_out, int out_size, void* d_ws, size_t ws_size,
                              hipStream_t stream) {
  const float* x  = (const float*)d_in[0];
  const float* W1 = (const float*)d_in[1];
  const float* W2 = (const float*)d_in[2];
  float* outp = (float*)d_out;

  float* z1 = (float*)d_ws;                       // [256,16,1000] = 16.384 MB
  const size_t Z1E = (size_t)B_ * HID_ * T_;
  const bool big = (ws_size >= 2 * Z1E * sizeof(float));
  float* s1 = big ? (z1 + Z1E) : z1;              // separate buffer or in-place

  mm1<<<dim3(B_ * 4), dim3(256), 0, stream>>>(x, W1, z1);
  if (big) {
    fir1<<<dim3(B_ * 8), dim3(256), 0, stream>>>(z1, s1, -1);
  } else {
    // in-place: process tiles in descending order; tile k only reads
    // t < 125(k+1), which later (higher) tiles never overwrote.
    for (int k = 7; k >= 0; --k)
      fir1<<<dim3(B_), dim3(256), 0, stream>>>(z1, s1, k);
  }
  l2fused<<<dim3(B_ * 8), dim3(320), 0, stream>>>(s1, W2, outp);
}

// Round 5
// 323.187 us; speedup vs baseline: 10.6743x; 3.8393x over previous
//
#include <hip/hip_runtime.h>
#include <math.h>

// SLAYER MLP forward: spike(psp(W2 @ spike(psp(W1 @ x))))
// B=256, IN=78, HID=16, OUT=20, T=1000, K=100 (SRM alpha, tau=10)
//
// fp64 accumulation everywhere (absmax 0.0 in rounds 0-3), fp32 rounding at
// reference materialization points (einsum outputs z1/z2, final u).
//
// Round-5 fix: mm2's W2 LDS load was `if (tid < 320)` with a 256-thread
// block -> wd[256..319] (output channels 16..19) uninitialized. Now a
// strided loop. Everything else identical to round 4.

#define B_     256
#define IN_    78
#define HID_   16
#define OUT_   20
#define T_     1000
#define TT_    125
#define J_     224              // TT + K - 1

// ---------------- FIR building blocks (named scalars only) ----------------
// Window W[0..10] = quads (A,B,C). Group with eps[s0..s0+3]:
//   u[d] += eps[s0+e] * W[d-e+3]
#define GRP(EP, A0,A1,A2,A3, B0,B1,B2,B3, C0,C1,C2) { \
  const double2 e01_ = *(const double2*)(EP); \
  const double2 e23_ = *(const double2*)((EP)+2); \
  u0 += e01_.x*(A3); u1 += e01_.x*(B0); u2 += e01_.x*(B1); u3 += e01_.x*(B2); \
  u4 += e01_.x*(B3); u5 += e01_.x*(C0); u6 += e01_.x*(C1); u7 += e01_.x*(C2); \
  u0 += e01_.y*(A2); u1 += e01_.y*(A3); u2 += e01_.y*(B0); u3 += e01_.y*(B1); \
  u4 += e01_.y*(B2); u5 += e01_.y*(B3); u6 += e01_.y*(C0); u7 += e01_.y*(C1); \
  u0 += e23_.x*(A1); u1 += e23_.x*(A2); u2 += e23_.x*(A3); u3 += e23_.x*(B0); \
  u4 += e23_.x*(B1); u5 += e23_.x*(B2); u6 += e23_.x*(B3); u7 += e23_.x*(C0); \
  u0 += e23_.y*(A0); u1 += e23_.y*(A1); u2 += e23_.y*(A2); u3 += e23_.y*(A3); \
  u4 += e23_.y*(B0); u5 += e23_.y*(B1); u6 += e23_.y*(B2); u7 += e23_.y*(B3); }

#define LOADD(X0,X1,X2,X3, P) { \
  const double2 la_ = *(const double2*)(P); \
  const double2 lb_ = *(const double2*)((P)+2); \
  X0 = la_.x; X1 = la_.y; X2 = lb_.x; X3 = lb_.y; }

// fp64-plane step: load quad c=24-G (plane by parity, slot q + (24-G)/2), GRP.
#define STEPD(G, N0,N1,N2,N3, P0,P1,P2,P3, Q0,Q1,Q2) \
  LOADD(N0,N1,N2,N3, ((((24-(G))&1) ? zo_row : ze_row) + 4*(q + ((24-(G))>>1)))); \
  GRP(eps_d + 4*(G), N0,N1,N2,N3, P0,P1,P2,P3, Q0,Q1,Q2)

#define FIR24_D \
  STEPD( 1, C0,C1,C2,C3, A0,A1,A2,A3, B0,B1,B2) \
  STEPD( 2, B0,B1,B2,B3, C0,C1,C2,C3, A0,A1,A2) \
  STEPD( 3, A0,A1,A2,A3, B0,B1,B2,B3, C0,C1,C2) \
  STEPD( 4, C0,C1,C2,C3, A0,A1,A2,A3, B0,B1,B2) \
  STEPD( 5, B0,B1,B2,B3, C0,C1,C2,C3, A0,A1,A2) \
  STEPD( 6, A0,A1,A2,A3, B0,B1,B2,B3, C0,C1,C2) \
  STEPD( 7, C0,C1,C2,C3, A0,A1,A2,A3, B0,B1,B2) \
  STEPD( 8, B0,B1,B2,B3, C0,C1,C2,C3, A0,A1,A2) \
  STEPD( 9, A0,A1,A2,A3, B0,B1,B2,B3, C0,C1,C2) \
  STEPD(10, C0,C1,C2,C3, A0,A1,A2,A3, B0,B1,B2) \
  STEPD(11, B0,B1,B2,B3, C0,C1,C2,C3, A0,A1,A2) \
  STEPD(12, A0,A1,A2,A3, B0,B1,B2,B3, C0,C1,C2) \
  STEPD(13, C0,C1,C2,C3, A0,A1,A2,A3, B0,B1,B2) \
  STEPD(14, B0,B1,B2,B3, C0,C1,C2,C3, A0,A1,A2) \
  STEPD(15, A0,A1,A2,A3, B0,B1,B2,B3, C0,C1,C2) \
  STEPD(16, C0,C1,C2,C3, A0,A1,A2,A3, B0,B1,B2) \
  STEPD(17, B0,B1,B2,B3, C0,C1,C2,C3, A0,A1,A2) \
  STEPD(18, A0,A1,A2,A3, B0,B1,B2,B3, C0,C1,C2) \
  STEPD(19, C0,C1,C2,C3, A0,A1,A2,A3, B0,B1,B2) \
  STEPD(20, B0,B1,B2,B3, C0,C1,C2,C3, A0,A1,A2) \
  STEPD(21, A0,A1,A2,A3, B0,B1,B2,B3, C0,C1,C2) \
  STEPD(22, C0,C1,C2,C3, A0,A1,A2,A3, B0,B1,B2) \
  STEPD(23, B0,B1,B2,B3, C0,C1,C2,C3, A0,A1,A2) \
  STEPD(24, A0,A1,A2,A3, B0,B1,B2,B3, C0,C1,C2)

__device__ __forceinline__ void init_eps_d(double* eps_d, int tid) {
  if (tid < 100) {
    float a = (float)tid / 10.0f;           // identical fp32 ops to reference
    float e = a * expf(1.0f - a);
    eps_d[tid] = (double)e;                 // exact widening
  }
}

// -------- mm1: z1[b,h,t] = sum_i W1[h,i] * x[b,i,t]  (proven clean) --------
// grid = 256 b * 4 t-chunks of 256; block 256 = 8 h-pairs x 32 t-octets
__global__ __launch_bounds__(256) void mm1(
    const float* __restrict__ x, const float* __restrict__ W1,
    float* __restrict__ z1)
{
  __shared__ double xe[13 * 128];
  __shared__ double xo[13 * 128];
  __shared__ double wd[16 * 80];

  const int tid = threadIdx.x;
  const int b   = blockIdx.x >> 2;
  const int tc  = blockIdx.x & 3;
  const int tcb = tc * 256;

  for (int idx = tid; idx < HID_ * IN_; idx += 256)
    wd[(idx / IN_) * 80 + (idx % IN_)] = (double)W1[idx];

  const int c    = tid;
  const int slot = ((c >> 3) << 2) | (c & 3);
  double* dst = (((c >> 2) & 1) ? xo : xe) + slot;
  const int t_c  = tcb + c;
  const bool cok = (t_c < T_);

  const int p = tid >> 5;
  const int q = tid & 31;

  double m00=0,m01=0,m02=0,m03=0,m04=0,m05=0,m06=0,m07=0;
  double m10=0,m11=0,m12=0,m13=0,m14=0,m15=0,m16=0,m17=0;

  for (int ci = 0; ci < 6; ++ci) {
    __syncthreads();
    {
      const float* xp = x + ((size_t)b * IN_ + ci * 13) * T_ + t_c;
#pragma unroll
      for (int r = 0; r < 13; ++r)
        dst[r * 128] = cok ? (double)xp[r * T_] : 0.0;
    }
    __syncthreads();
#pragma unroll
    for (int i = 0; i < 13; ++i) {
      double d0,d1,d2,d3,d4,d5,d6,d7;
      LOADD(d0,d1,d2,d3, &xe[i * 128 + 4 * q]);
      LOADD(d4,d5,d6,d7, &xo[i * 128 + 4 * q]);
      const double w0 = wd[(2*p)     * 80 + ci * 13 + i];
      const double w1 = wd[(2*p + 1) * 80 + ci * 13 + i];
      m00 += w0*d0; m01 += w0*d1; m02 += w0*d2; m03 += w0*d3;
      m04 += w0*d4; m05 += w0*d5; m06 += w0*d6; m07 += w0*d7;
      m10 += w1*d0; m11 += w1*d1; m12 += w1*d2; m13 += w1*d3;
      m14 += w1*d4; m15 += w1*d5; m16 += w1*d6; m17 += w1*d7;
    }
  }

  const int t8 = tcb + 8 * q;
  if (t8 + 7 < T_) {
    float* o0 = &z1[((size_t)b * HID_ + 2*p) * T_ + t8];
    float* o1 = &z1[((size_t)b * HID_ + 2*p + 1) * T_ + t8];
    *(float4*)(o0)     = make_float4((float)m00,(float)m01,(float)m02,(float)m03);
    *(float4*)(o0 + 4) = make_float4((float)m04,(float)m05,(float)m06,(float)m07);
    *(float4*)(o1)     = make_float4((float)m10,(float)m11,(float)m12,(float)m13);
    *(float4*)(o1 + 4) = make_float4((float)m14,(float)m15,(float)m16,(float)m17);
  }
}

// -------- mm2: z2[b,o,t] = sum_h W2[o,h] * s1[b,h,t] -----------------------
// Same shape as mm1; pair-loop covers 10 o-pairs with 8 p-slots.
__global__ __launch_bounds__(256) void mm2(
    const float* __restrict__ s1, const float* __restrict__ W2,
    float* __restrict__ z2)
{
  __shared__ double se[16 * 128];
  __shared__ double so[16 * 128];
  __shared__ double wd[OUT_ * HID_];

  const int tid = threadIdx.x;
  const int b   = blockIdx.x >> 2;
  const int tc  = blockIdx.x & 3;
  const int tcb = tc * 256;

  // FIX (round-5): strided loop — OUT_*HID_ = 320 > blockDim 256; the round-4
  // `if (tid < 320)` left wd[256..319] (output chans 16..19) uninitialized.
  for (int idx = tid; idx < OUT_ * HID_; idx += 256)
    wd[idx] = (double)W2[idx];

  const int c    = tid;
  const int slot = ((c >> 3) << 2) | (c & 3);
  double* dst = (((c >> 2) & 1) ? so : se) + slot;
  const int t_c  = tcb + c;
  const bool cok = (t_c < T_);
  {
    const float* sp = s1 + (size_t)b * HID_ * T_ + t_c;
#pragma unroll
    for (int r = 0; r < HID_; ++r)
      dst[r * 128] = cok ? (double)sp[r * T_] : 0.0;
  }
  __syncthreads();

  const int p  = tid >> 5;
  const int q  = tid & 31;
  const int t8 = tcb + 8 * q;

  for (int pg = p; pg < 10; pg += 8) {   // p in {0,1} handles a second pair
    double m00=0,m01=0,m02=0,m03=0,m04=0,m05=0,m06=0,m07=0;
    double m10=0,m11=0,m12=0,m13=0,m14=0,m15=0,m16=0,m17=0;
#pragma unroll
    for (int i = 0; i < HID_; ++i) {
      double d0,d1,d2,d3,d4,d5,d6,d7;
      LOADD(d0,d1,d2,d3, &se[i * 128 + 4 * q]);
      LOADD(d4,d5,d6,d7, &so[i * 128 + 4 * q]);
      const double w0 = wd[(2*pg)     * HID_ + i];
      const double w1 = wd[(2*pg + 1) * HID_ + i];
      m00 += w0*d0; m01 += w0*d1; m02 += w0*d2; m03 += w0*d3;
      m04 += w0*d4; m05 += w0*d5; m06 += w0*d6; m07 += w0*d7;
      m10 += w1*d0; m11 += w1*d1; m12 += w1*d2; m13 += w1*d3;
      m14 += w1*d4; m15 += w1*d5; m16 += w1*d6; m17 += w1*d7;
    }
    if (t8 + 7 < T_) {
      float* o0 = &z2[((size_t)b * OUT_ + 2*pg) * T_ + t8];
      float* o1 = &z2[((size_t)b * OUT_ + 2*pg + 1) * T_ + t8];
      *(float4*)(o0)     = make_float4((float)m00,(float)m01,(float)m02,(float)m03);
      *(float4*)(o0 + 4) = make_float4((float)m04,(float)m05,(float)m06,(float)m07);
      *(float4*)(o1)     = make_float4((float)m10,(float)m11,(float)m12,(float)m13);
      *(float4*)(o1 + 4) = make_float4((float)m14,(float)m15,(float)m16,(float)m17);
    }
  }
}

// -------- fir_g: sout = spike(FIR(zin)), R rows (16 or 20) -----------------
// tile_fixed < 0: grid = B*8; else grid = B, single tile (in-place safe when
// tiles launched in DESCENDING order; tile k reads t < 125(k+1)).
__global__ __launch_bounds__(256) void fir_g(
    const float* __restrict__ zin, float* __restrict__ sout,
    int R, int tile_fixed)
{
  __shared__ double ze[OUT_ * 116];   // sized for R<=20
  __shared__ double zo[OUT_ * 116];
  __shared__ __align__(16) double eps_d[100];

  const int tid  = threadIdx.x;
  const int b    = (tile_fixed >= 0) ? (int)blockIdx.x : (int)(blockIdx.x >> 3);
  const int tile = (tile_fixed >= 0) ? tile_fixed      : (int)(blockIdx.x & 7);
  const int t0   = tile * TT_;

  init_eps_d(eps_d, tid);
  for (int idx = tid; idx < R * J_; idx += 256) {
    const int r = idx / J_, cc = idx % J_;
    const int t = t0 - 99 + cc;
    const double v = (t >= 0) ? (double)zin[((size_t)b * R + r) * T_ + t] : 0.0;
    double* pl = (((cc >> 2) & 1) ? zo : ze);
    pl[r * 116 + (((cc >> 3) << 2) | (cc & 3))] = v;
  }
  __syncthreads();

  for (int task = tid; task < R * 16; task += 256) {
    const int h = task >> 4, q = task & 15;
    const double* ze_row = &ze[h * 116];
    const double* zo_row = &zo[h * 116];
    double u0=0,u1=0,u2=0,u3=0,u4=0,u5=0,u6=0,u7=0;
    double A0,A1,A2,A3,B0,B1,B2,B3,C0,C1,C2,C3;
    LOADD(A0,A1,A2,A3, ze_row + 4*(q + 12));     // quad c=24
    LOADD(B0,B1,B2,B3, zo_row + 4*(q + 12));     // quad c=25
    LOADD(C0,C1,C2,C3, ze_row + 4*(q + 13));     // quad c=26
    GRP(eps_d, A0,A1,A2,A3, B0,B1,B2,B3, C0,C1,C2)
    FIR24_D

    const size_t base = ((size_t)b * R + h) * T_ + t0 + 8 * q;
    const int tb = 8 * q;
    const float f0=(float)u0, f1=(float)u1, f2=(float)u2, f3=(float)u3;
    const float f4=(float)u4, f5=(float)u5, f6=(float)u6, f7=(float)u7;
    sout[base + 0] = (f0 >= 1.0f) ? 1.0f : 0.0f;   // tb+3 <= 123 always valid
    sout[base + 1] = (f1 >= 1.0f) ? 1.0f : 0.0f;
    sout[base + 2] = (f2 >= 1.0f) ? 1.0f : 0.0f;
    sout[base + 3] = (f3 >= 1.0f) ? 1.0f : 0.0f;
    if (tb + 4 < TT_) sout[base + 4] = (f4 >= 1.0f) ? 1.0f : 0.0f;
    if (tb + 5 < TT_) sout[base + 5] = (f5 >= 1.0f) ? 1.0f : 0.0f;
    if (tb + 6 < TT_) sout[base + 6] = (f6 >= 1.0f) ? 1.0f : 0.0f;
    if (tb + 7 < TT_) sout[base + 7] = (f7 >= 1.0f) ? 1.0f : 0.0f;
  }
}

extern "C" void kernel_launch(void* const* d_in, const int* in_sizes, int n_in,
                              void* d_out, int out_size, void* d_ws, size_t ws_size,
                              hipStream_t stream) {
  const float* x  = (const float*)d_in[0];
  const float* W1 = (const float*)d_in[1];
  const float* W2 = (const float*)d_in[2];
  float* outp = (float*)d_out;
  float* base = (float*)d_ws;

  const size_t Z1E = (size_t)B_ * HID_ * T_;   // 4.096M floats (16.4 MB)
  const size_t Z2E = (size_t)B_ * OUT_ * T_;   // 5.120M floats (20.5 MB)

  if (ws_size >= (Z1E + Z2E) * sizeof(float)) {
    // z1 @ base (dead after fir1), s1 @ base+Z2E, z2 @ base (reuses z1 space)
    float* z1 = base;
    float* s1 = base + Z2E;
    float* z2 = base;
    mm1<<<dim3(B_ * 4), dim3(256), 0, stream>>>(x, W1, z1);
    fir_g<<<dim3(B_ * 8), dim3(256), 0, stream>>>(z1, s1, HID_, -1);
    mm2<<<dim3(B_ * 4), dim3(256), 0, stream>>>(s1, W2, z2);
    fir_g<<<dim3(B_ * 8), dim3(256), 0, stream>>>(z2, outp, OUT_, -1);
  } else if (ws_size >= 2 * Z1E * sizeof(float)) {
    // z2 lives in d_out; fir2 runs in-place with descending tiles
    float* z1 = base;
    float* s1 = base + Z1E;
    mm1<<<dim3(B_ * 4), dim3(256), 0, stream>>>(x, W1, z1);
    fir_g<<<dim3(B_ * 8), dim3(256), 0, stream>>>(z1, s1, HID_, -1);
    mm2<<<dim3(B_ * 4), dim3(256), 0, stream>>>(s1, W2, outp);
    for (int k = 7; k >= 0; --k)
      fir_g<<<dim3(B_), dim3(256), 0, stream>>>(outp, outp, OUT_, k);
  } else {
    // minimal ws: layer-1 in-place too
    float* z1 = base;
    mm1<<<dim3(B_ * 4), dim3(256), 0, stream>>>(x, W1, z1);
    for (int k = 7; k >= 0; --k)
      fir_g<<<dim3(B_), dim3(256), 0, stream>>>(z1, z1, HID_, k);
    mm2<<<dim3(B_ * 4), dim3(256), 0, stream>>>(z1, W2, outp);
    for (int k = 7; k >= 0; --k)
      fir_g<<<dim3(B_), dim3(256), 0, stream>>>(outp, outp, OUT_, k);
  }
}